// Round 11
// baseline (1933.593 us; speedup 1.0000x reference)
//
#include <hip/hip_runtime.h>

#define NNODES 50000
#define HDIM 256
#define NLAYERS 4
#define NEDGES 800000
#define FIN 1280
#define LDOUT 1024

typedef _Float16 f16;
typedef __attribute__((ext_vector_type(8))) _Float16 f16x8;
typedef __attribute__((ext_vector_type(4))) _Float16 f16x4;
typedef __attribute__((ext_vector_type(4))) float f32x4;

enum { SRC_H = 0, SRC_MULH = 1 };

// ---------------------------------------------------------------------------
// Frag-major LDS layout for a 64row x 256k f16 A-panel (32 KB):
//   k-col c, row r ->  region = (c>>6)*8 + ((c>>5)&1)*4 + (r>>4)
//                      slot   = ((c&31)>>3)*16 + (r&15),  elem = c&7
//   addr(f16) = (region*64 + slot)*8 + elem
// Read side (MFMA A-frag, tile kt, kb, rf, lane l):
//   addr = ((kt*8 + kb*4 + rf)*64 + l)*8    (l>>4 = 8-col chunk, l&15 = row)
// MFMA layouts refcheck-validated R3-R10: A row=l&15, k=(l>>4)*8+j (+32kb);
// B col=l&15 (col-major Wt); C/D col=l&15, row=(l>>4)*4+reg.
// ---------------------------------------------------------------------------

// ---------------------------------------------------------------------------
// W2W1 GEMM (R10 structure, verified): BM=64 x BN=256, BK=64, LDS dbuf +
// depth-2 reg prefetch.  blockIdx.y selects W2 (y0 -> hnb) / W1 (y1 -> xw1h).
// ---------------------------------------------------------------------------
template<int SRC>
__global__ __launch_bounds__(256) void w2w1_k(
    const f16*  __restrict__ A3,      // xcur
    const f16*  __restrict__ A5,      // maskh (MULH)
    const f16*  __restrict__ Wt,      // W2 [256][256] col-major
    const f16*  __restrict__ Wt2,     // W1
    const float* __restrict__ bias,   // b2
    const float* __restrict__ bias2,  // b1
    f16*  __restrict__ Ch,            // hnb
    f16*  __restrict__ Ch2)           // xw1h
{
    constexpr int KTILES = 4;
    constexpr int K = 256;
    __shared__ f16 Asm[2][4096];

    const int row0 = blockIdx.x * 64;
    const int by = blockIdx.y;
    const int tid = threadIdx.x;
    const int wv = tid >> 6;
    const int l = tid & 63;

    f32x4 acc[4][4] = {};

    const int sr = tid >> 2;
    const int sc0 = (tid & 3) * 16;
    const int grow = row0 + sr;
    const bool rok = grow < NNODES;
    const int lane_base0 =
        (((sc0 >> 5) * 4 + (sr >> 4)) * 64 + (sr & 15) + (((sc0 & 31) >> 3) * 16)) * 8;
    const int lane_base1 = lane_base0 + 128;

    const f16* Wsel = by ? Wt2 : Wt;
    const f16* bp[4];
    #pragma unroll
    for (int cf = 0; cf < 4; ++cf)
        bp[cf] = Wsel + (size_t)(wv * 64 + cf * 16 + (l & 15)) * K + ((l >> 4) * 8);

    struct SReg { f16x8 h0, h1, g0, g1; };
    SReg RA, RB;

    auto LOAD = [&](SReg& r, int kt) {
        if (!rok) return;
        const int k0 = kt * 64 + sc0;
        const f16* p = A3 + (size_t)grow * HDIM + k0;
        r.h0 = *(const f16x8*)p;  r.h1 = *(const f16x8*)(p + 8);
        if constexpr (SRC == SRC_MULH) {
            const f16* q = A5 + (size_t)grow * HDIM + k0;
            r.g0 = *(const f16x8*)q;  r.g1 = *(const f16x8*)(q + 8);
        }
    };

    auto COMMIT = [&](const SReg& r, int b) {
        f16x8 av0, av1;
        #pragma unroll
        for (int i = 0; i < 8; ++i) { av0[i] = (f16)0.f; av1[i] = (f16)0.f; }
        if (rok) {
            if constexpr (SRC == SRC_H) {
                av0 = r.h0; av1 = r.h1;
            } else {
                #pragma unroll
                for (int i = 0; i < 8; ++i) {
                    av0[i] = (f16)((float)r.h0[i] * (float)r.g0[i]);
                    av1[i] = (f16)((float)r.h1[i] * (float)r.g1[i]);
                }
            }
        }
        *(f16x8*)(&Asm[b][lane_base0]) = av0;
        *(f16x8*)(&Asm[b][lane_base1]) = av1;
    };

    auto TILE = [&](int b, int kt) {
        f16x8 af[4][2];
        #pragma unroll
        for (int rf = 0; rf < 4; ++rf)
            #pragma unroll
            for (int kb = 0; kb < 2; ++kb)
                af[rf][kb] = *(const f16x8*)(&Asm[b][((kb * 4 + rf) * 64 + l) * 8]);
        f16x8 bfr[4][2];
        #pragma unroll
        for (int cf = 0; cf < 4; ++cf) {
            bfr[cf][0] = *(const f16x8*)(bp[cf] + kt * 64);
            bfr[cf][1] = *(const f16x8*)(bp[cf] + kt * 64 + 32);
        }
        #pragma unroll
        for (int cf = 0; cf < 4; ++cf)
            #pragma unroll
            for (int rf = 0; rf < 4; ++rf)
                #pragma unroll
                for (int kb = 0; kb < 2; ++kb)
                    acc[rf][cf] = __builtin_amdgcn_mfma_f32_16x16x32_f16(
                        af[rf][kb], bfr[cf][kb], acc[rf][cf], 0, 0, 0);
    };

    LOAD(RA, 0);
    COMMIT(RA, 0);
    LOAD(RB, 1);
    #pragma unroll
    for (int kt2 = 0; kt2 < KTILES; kt2 += 2) {
        __syncthreads();
        TILE(0, kt2);
        COMMIT(RB, 1);
        if (kt2 + 2 < KTILES) LOAD(RA, kt2 + 2);
        __syncthreads();
        TILE(1, kt2 + 1);
        if (kt2 + 2 < KTILES) COMMIT(RA, 0);
        if (kt2 + 3 < KTILES) LOAD(RB, kt2 + 3);
    }

    #pragma unroll
    for (int rf = 0; rf < 4; ++rf) {
        #pragma unroll
        for (int j = 0; j < 4; ++j) {
            const int row = row0 + rf * 16 + ((l >> 4) * 4) + j;
            if (row >= NNODES) continue;
            #pragma unroll
            for (int cf = 0; cf < 4; ++cf) {
                const int col = wv * 64 + cf * 16 + (l & 15);
                float v = acc[rf][cf][j];
                if (by == 0) Ch[(size_t)row * HDIM + col]  = (f16)(v + bias[col]);
                else         Ch2[(size_t)row * HDIM + col] = (f16)(v + bias2[col]);
            }
        }
    }
}

// ---------------------------------------------------------------------------
// Fused gather1 + mask GEMM (g1m):
// phase1: per wave, 16 nodes: agg=sum(hnb[nbrs]); A=relu(agg+xw1h) -> frag LDS
// phase2: barrier-free GEMM (A in LDS, B reg-prefetched)
// epilogue: m=sigmoid(v+b3) -> maskh; xg = xcur*m
// ---------------------------------------------------------------------------
__global__ __launch_bounds__(256) void g1m_k(
    const f16* __restrict__ hnb,
    const int* __restrict__ csr, const int* __restrict__ starts,
    const f16* __restrict__ xw1h,
    const f16* __restrict__ xcur,
    const f16* __restrict__ W3t,      // [256][256] col-major
    const float* __restrict__ b3,
    f16* __restrict__ maskh,
    f16* __restrict__ xg)
{
    __shared__ f16 Afr[32 * 64 * 8];  // 32 KB frag-major, K=256

    const int tid = threadIdx.x;
    const int l = tid & 63;
    const int wv = tid >> 6;
    const int row0 = blockIdx.x * 64;

    // ---- phase 1: gather + add + relu -> frag-major LDS
    const int c = l * 4;
    const int region_c = ((c >> 6) << 3) + (((c >> 5) & 1) << 2);
    const int slot_c = (((c & 31) >> 3) << 4);
    for (int t = 0; t < 16; ++t) {
        const int srow = wv * 16 + t;
        const int node = row0 + srow;
        float r0 = 0.f, r1 = 0.f, r2 = 0.f, r3 = 0.f;
        if (node < NNODES) {
            const int e0 = starts[node], e1 = starts[node + 1];
            float s0=0,s1=0,s2=0,s3=0, u0=0,u1=0,u2=0,u3=0;
            int e = e0;
            for (; e + 3 < e1; e += 4) {
                const int q0=csr[e], q1=csr[e+1], q2=csr[e+2], q3=csr[e+3];
                f16x4 v0 = *(const f16x4*)(hnb + (size_t)q0 * HDIM + c);
                f16x4 v1 = *(const f16x4*)(hnb + (size_t)q1 * HDIM + c);
                f16x4 v2 = *(const f16x4*)(hnb + (size_t)q2 * HDIM + c);
                f16x4 v3 = *(const f16x4*)(hnb + (size_t)q3 * HDIM + c);
                s0 += (float)v0[0] + (float)v2[0]; s1 += (float)v0[1] + (float)v2[1];
                s2 += (float)v0[2] + (float)v2[2]; s3 += (float)v0[3] + (float)v2[3];
                u0 += (float)v1[0] + (float)v3[0]; u1 += (float)v1[1] + (float)v3[1];
                u2 += (float)v1[2] + (float)v3[2]; u3 += (float)v1[3] + (float)v3[3];
            }
            for (; e < e1; ++e) {
                const int q0 = csr[e];
                f16x4 v0 = *(const f16x4*)(hnb + (size_t)q0 * HDIM + c);
                s0 += (float)v0[0]; s1 += (float)v0[1];
                s2 += (float)v0[2]; s3 += (float)v0[3];
            }
            const f16x4 w = *(const f16x4*)(xw1h + (size_t)node * HDIM + c);
            r0 = fmaxf(s0 + u0 + (float)w[0], 0.f);
            r1 = fmaxf(s1 + u1 + (float)w[1], 0.f);
            r2 = fmaxf(s2 + u2 + (float)w[2], 0.f);
            r3 = fmaxf(s3 + u3 + (float)w[3], 0.f);
        }
        f16x4 st;
        st[0] = (f16)r0; st[1] = (f16)r1; st[2] = (f16)r2; st[3] = (f16)r3;
        const int region = region_c + (srow >> 4);
        const int slot = slot_c + (srow & 15);
        *(f16x4*)(&Afr[((region << 6) + slot) * 8 + (c & 7)]) = st;
    }
    __syncthreads();

    // ---- phase 2: GEMM 64x256, K=256, A in LDS (no more barriers)
    const f16* bp[4];
    #pragma unroll
    for (int cf = 0; cf < 4; ++cf)
        bp[cf] = W3t + (size_t)(wv * 64 + cf * 16 + (l & 15)) * 256 + ((l >> 4) * 8);

    f32x4 acc[4][4] = {};
    f16x8 bC[4][2], bN[4][2];
    #pragma unroll
    for (int cf = 0; cf < 4; ++cf) {
        bC[cf][0] = *(const f16x8*)(bp[cf]);
        bC[cf][1] = *(const f16x8*)(bp[cf] + 32);
    }
    #pragma unroll
    for (int kt = 0; kt < 4; ++kt) {
        if (kt < 3) {
            #pragma unroll
            for (int cf = 0; cf < 4; ++cf) {
                bN[cf][0] = *(const f16x8*)(bp[cf] + (kt + 1) * 64);
                bN[cf][1] = *(const f16x8*)(bp[cf] + (kt + 1) * 64 + 32);
            }
        }
        f16x8 af[4][2];
        #pragma unroll
        for (int rf = 0; rf < 4; ++rf)
            #pragma unroll
            for (int kb = 0; kb < 2; ++kb)
                af[rf][kb] = *(const f16x8*)(&Afr[((kt * 8 + kb * 4 + rf) * 64 + l) * 8]);
        #pragma unroll
        for (int cf = 0; cf < 4; ++cf)
            #pragma unroll
            for (int rf = 0; rf < 4; ++rf)
                #pragma unroll
                for (int kb = 0; kb < 2; ++kb)
                    acc[rf][cf] = __builtin_amdgcn_mfma_f32_16x16x32_f16(
                        af[rf][kb], bC[cf][kb], acc[rf][cf], 0, 0, 0);
        if (kt < 3) {
            #pragma unroll
            for (int cf = 0; cf < 4; ++cf) {
                bC[cf][0] = bN[cf][0];  bC[cf][1] = bN[cf][1];
            }
        }
    }

    // ---- epilogue: mask + xg
    #pragma unroll
    for (int rf = 0; rf < 4; ++rf) {
        #pragma unroll
        for (int j = 0; j < 4; ++j) {
            const int row = row0 + rf * 16 + ((l >> 4) * 4) + j;
            if (row >= NNODES) continue;
            #pragma unroll
            for (int cf = 0; cf < 4; ++cf) {
                const int col = wv * 64 + cf * 16 + (l & 15);
                const float m = 1.f / (1.f + expf(-(acc[rf][cf][j] + b3[col])));
                maskh[(size_t)row * HDIM + col] = (f16)m;
                xg[(size_t)row * HDIM + col] =
                    (f16)((float)xcur[(size_t)row * HDIM + col] * m);
            }
        }
    }
}

// ---------------------------------------------------------------------------
// Fused gather2 + CATH GEMM (g2c):
// phase1: agg2 = sum(xg[nbrs]) -> frag LDS (k-tiles 0-3)
// phase2: K=512 GEMM; A tiles 0-3 LDS, tiles 4-7 direct-from-global xcur
// epilogue: r = relu(v+bn) -> out (f32 ld 1024) + xnew (f16)
// ---------------------------------------------------------------------------
__global__ __launch_bounds__(256) void g2c_k(
    const f16* __restrict__ xg,
    const int* __restrict__ csr, const int* __restrict__ starts,
    const f16* __restrict__ xcur,
    const f16* __restrict__ WtC,      // [256][512] col-major
    const float* __restrict__ bn,
    float* __restrict__ outp,
    f16* __restrict__ xnew)
{
    __shared__ f16 Afr[32 * 64 * 8];  // 32 KB frag-major (agg2, K=256)

    const int tid = threadIdx.x;
    const int l = tid & 63;
    const int wv = tid >> 6;
    const int row0 = blockIdx.x * 64;

    // ---- phase 1: gather xg -> frag-major LDS
    const int c = l * 4;
    const int region_c = ((c >> 6) << 3) + (((c >> 5) & 1) << 2);
    const int slot_c = (((c & 31) >> 3) << 4);
    for (int t = 0; t < 16; ++t) {
        const int srow = wv * 16 + t;
        const int node = row0 + srow;
        float r0 = 0.f, r1 = 0.f, r2 = 0.f, r3 = 0.f;
        if (node < NNODES) {
            const int e0 = starts[node], e1 = starts[node + 1];
            float s0=0,s1=0,s2=0,s3=0, u0=0,u1=0,u2=0,u3=0;
            int e = e0;
            for (; e + 3 < e1; e += 4) {
                const int q0=csr[e], q1=csr[e+1], q2=csr[e+2], q3=csr[e+3];
                f16x4 v0 = *(const f16x4*)(xg + (size_t)q0 * HDIM + c);
                f16x4 v1 = *(const f16x4*)(xg + (size_t)q1 * HDIM + c);
                f16x4 v2 = *(const f16x4*)(xg + (size_t)q2 * HDIM + c);
                f16x4 v3 = *(const f16x4*)(xg + (size_t)q3 * HDIM + c);
                s0 += (float)v0[0] + (float)v2[0]; s1 += (float)v0[1] + (float)v2[1];
                s2 += (float)v0[2] + (float)v2[2]; s3 += (float)v0[3] + (float)v2[3];
                u0 += (float)v1[0] + (float)v3[0]; u1 += (float)v1[1] + (float)v3[1];
                u2 += (float)v1[2] + (float)v3[2]; u3 += (float)v1[3] + (float)v3[3];
            }
            for (; e < e1; ++e) {
                const int q0 = csr[e];
                f16x4 v0 = *(const f16x4*)(xg + (size_t)q0 * HDIM + c);
                s0 += (float)v0[0]; s1 += (float)v0[1];
                s2 += (float)v0[2]; s3 += (float)v0[3];
            }
            r0 = s0 + u0; r1 = s1 + u1; r2 = s2 + u2; r3 = s3 + u3;
        }
        f16x4 st;
        st[0] = (f16)r0; st[1] = (f16)r1; st[2] = (f16)r2; st[3] = (f16)r3;
        const int region = region_c + (srow >> 4);
        const int slot = slot_c + (srow & 15);
        *(f16x4*)(&Afr[((region << 6) + slot) * 8 + (c & 7)]) = st;
    }
    __syncthreads();

    // ---- phase 2: K=512 GEMM (tiles 0-3 LDS, 4-7 global xcur)
    const f16* bp[4];
    #pragma unroll
    for (int cf = 0; cf < 4; ++cf)
        bp[cf] = WtC + (size_t)(wv * 64 + cf * 16 + (l & 15)) * 512 + ((l >> 4) * 8);

    // per-rf row validity for direct global A loads
    bool rvalid[4];
    const f16* xrow[4];
    #pragma unroll
    for (int rf = 0; rf < 4; ++rf) {
        const int ar = row0 + rf * 16 + (l & 15);
        rvalid[rf] = ar < NNODES;
        xrow[rf] = xcur + (size_t)ar * HDIM + ((l >> 4) * 8);
    }

    f32x4 acc[4][4] = {};
    f16x8 bC[4][2], bN[4][2];
    #pragma unroll
    for (int cf = 0; cf < 4; ++cf) {
        bC[cf][0] = *(const f16x8*)(bp[cf]);
        bC[cf][1] = *(const f16x8*)(bp[cf] + 32);
    }
    #pragma unroll
    for (int kt = 0; kt < 8; ++kt) {
        if (kt < 7) {
            #pragma unroll
            for (int cf = 0; cf < 4; ++cf) {
                bN[cf][0] = *(const f16x8*)(bp[cf] + (kt + 1) * 64);
                bN[cf][1] = *(const f16x8*)(bp[cf] + (kt + 1) * 64 + 32);
            }
        }
        f16x8 af[4][2];
        if (kt < 4) {
            #pragma unroll
            for (int rf = 0; rf < 4; ++rf)
                #pragma unroll
                for (int kb = 0; kb < 2; ++kb)
                    af[rf][kb] = *(const f16x8*)(&Afr[((kt * 8 + kb * 4 + rf) * 64 + l) * 8]);
        } else {
            #pragma unroll
            for (int rf = 0; rf < 4; ++rf)
                #pragma unroll
                for (int kb = 0; kb < 2; ++kb) {
                    f16x8 v;
                    #pragma unroll
                    for (int i = 0; i < 8; ++i) v[i] = (f16)0.f;
                    if (rvalid[rf])
                        v = *(const f16x8*)(xrow[rf] + (kt - 4) * 64 + kb * 32);
                    af[rf][kb] = v;
                }
        }
        #pragma unroll
        for (int cf = 0; cf < 4; ++cf)
            #pragma unroll
            for (int rf = 0; rf < 4; ++rf)
                #pragma unroll
                for (int kb = 0; kb < 2; ++kb)
                    acc[rf][cf] = __builtin_amdgcn_mfma_f32_16x16x32_f16(
                        af[rf][kb], bC[cf][kb], acc[rf][cf], 0, 0, 0);
        if (kt < 7) {
            #pragma unroll
            for (int cf = 0; cf < 4; ++cf) {
                bC[cf][0] = bN[cf][0];  bC[cf][1] = bN[cf][1];
            }
        }
    }

    // ---- epilogue: out + xnew (xnew != xcur -> no alias race)
    #pragma unroll
    for (int rf = 0; rf < 4; ++rf) {
        #pragma unroll
        for (int j = 0; j < 4; ++j) {
            const int row = row0 + rf * 16 + ((l >> 4) * 4) + j;
            if (row >= NNODES) continue;
            #pragma unroll
            for (int cf = 0; cf < 4; ++cf) {
                const int col = wv * 64 + cf * 16 + (l & 15);
                const float r = fmaxf(acc[rf][cf][j] + bn[col], 0.f);
                outp[(size_t)row * LDOUT + col] = r;
                xnew[(size_t)row * HDIM + col] = (f16)r;
            }
        }
    }
}

// ---------------------------------------------------------------------------
// lin0 GEMM (verified R7-R10, 149us): K-split x2 via blockIdx.y.
// ---------------------------------------------------------------------------
template<int KTILES>
__global__ __launch_bounds__(256) void lin0_k(
    const float* __restrict__ A1, int lda1,
    const f16*  __restrict__ WtA, const f16* __restrict__ WtB,
    float* __restrict__ Cf, float* __restrict__ Cf2)
{
    constexpr int K = KTILES * 64;
    __shared__ f16 Asm[2][4096];

    const int row0 = blockIdx.x * 64;
    const int by = blockIdx.y;
    const int tid = threadIdx.x;
    const int wv = tid >> 6;
    const int l = tid & 63;

    f32x4 acc[4][4] = {};

    const int sr = tid >> 2;
    const int sc0 = (tid & 3) * 16;
    const int grow = row0 + sr;
    const bool rok = grow < NNODES;
    const int kg = by * K;
    const int lane_base0 =
        (((sc0 >> 5) * 4 + (sr >> 4)) * 64 + (sr & 15) + (((sc0 & 31) >> 3) * 16)) * 8;
    const int lane_base1 = lane_base0 + 128;

    const f16* Wsel = by ? WtB : WtA;
    const f16* bp[4];
    #pragma unroll
    for (int cf = 0; cf < 4; ++cf)
        bp[cf] = Wsel + (size_t)(wv * 64 + cf * 16 + (l & 15)) * K + ((l >> 4) * 8);

    struct SReg { float4 f0, f1, f2, f3; };
    SReg RA, RB;

    auto LOAD = [&](SReg& r, int kt) {
        if (!rok) return;
        const float* p = A1 + (size_t)grow * lda1 + kg + kt * 64 + sc0;
        r.f0 = *(const float4*)(p + 0);  r.f1 = *(const float4*)(p + 4);
        r.f2 = *(const float4*)(p + 8);  r.f3 = *(const float4*)(p + 12);
    };

    auto COMMIT = [&](const SReg& r, int b) {
        f16x8 av0, av1;
        #pragma unroll
        for (int i = 0; i < 8; ++i) { av0[i] = (f16)0.f; av1[i] = (f16)0.f; }
        if (rok) {
            av0[0]=(f16)r.f0.x; av0[1]=(f16)r.f0.y; av0[2]=(f16)r.f0.z; av0[3]=(f16)r.f0.w;
            av0[4]=(f16)r.f1.x; av0[5]=(f16)r.f1.y; av0[6]=(f16)r.f1.z; av0[7]=(f16)r.f1.w;
            av1[0]=(f16)r.f2.x; av1[1]=(f16)r.f2.y; av1[2]=(f16)r.f2.z; av1[3]=(f16)r.f2.w;
            av1[4]=(f16)r.f3.x; av1[5]=(f16)r.f3.y; av1[6]=(f16)r.f3.z; av1[7]=(f16)r.f3.w;
        }
        *(f16x8*)(&Asm[b][lane_base0]) = av0;
        *(f16x8*)(&Asm[b][lane_base1]) = av1;
    };

    auto TILE = [&](int b, int kt) {
        f16x8 af[4][2];
        #pragma unroll
        for (int rf = 0; rf < 4; ++rf)
            #pragma unroll
            for (int kb = 0; kb < 2; ++kb)
                af[rf][kb] = *(const f16x8*)(&Asm[b][((kb * 4 + rf) * 64 + l) * 8]);
        f16x8 bfr[4][2];
        #pragma unroll
        for (int cf = 0; cf < 4; ++cf) {
            bfr[cf][0] = *(const f16x8*)(bp[cf] + kt * 64);
            bfr[cf][1] = *(const f16x8*)(bp[cf] + kt * 64 + 32);
        }
        #pragma unroll
        for (int cf = 0; cf < 4; ++cf)
            #pragma unroll
            for (int rf = 0; rf < 4; ++rf)
                #pragma unroll
                for (int kb = 0; kb < 2; ++kb)
                    acc[rf][cf] = __builtin_amdgcn_mfma_f32_16x16x32_f16(
                        af[rf][kb], bfr[cf][kb], acc[rf][cf], 0, 0, 0);
    };

    LOAD(RA, 0);
    COMMIT(RA, 0);
    if (KTILES > 1) LOAD(RB, 1);
    #pragma unroll
    for (int kt2 = 0; kt2 < KTILES; kt2 += 2) {
        __syncthreads();
        TILE(0, kt2);
        if (kt2 + 1 < KTILES) COMMIT(RB, 1);
        if (kt2 + 2 < KTILES) LOAD(RA, kt2 + 2);
        if (kt2 + 1 < KTILES) {
            __syncthreads();
            TILE(1, kt2 + 1);
            if (kt2 + 2 < KTILES) COMMIT(RA, 0);
            if (kt2 + 3 < KTILES) LOAD(RB, kt2 + 3);
        }
    }

    #pragma unroll
    for (int rf = 0; rf < 4; ++rf) {
        #pragma unroll
        for (int j = 0; j < 4; ++j) {
            const int row = row0 + rf * 16 + ((l >> 4) * 4) + j;
            if (row >= NNODES) continue;
            #pragma unroll
            for (int cf = 0; cf < 4; ++cf) {
                const int col = wv * 64 + cf * 16 + (l & 15);
                (by ? Cf2 : Cf)[(size_t)row * HDIM + col] = acc[rf][cf][j];
            }
        }
    }
}

__global__ __launch_bounds__(256) void combine_k(
    const float* __restrict__ P0, const float* __restrict__ P1,
    const float* __restrict__ b, f16* __restrict__ xh)
{
    const int t = blockIdx.x * 256 + threadIdx.x;
    const int row = t >> 6;
    const int c = (t & 63) * 4;
    if (row >= NNODES) return;
    const float4 a = *(const float4*)(P0 + (size_t)row * HDIM + c);
    const float4 d = *(const float4*)(P1 + (size_t)row * HDIM + c);
    const float4 bb = *(const float4*)(b + c);
    f16x4 r;
    r[0] = (f16)(a.x + d.x + bb.x); r[1] = (f16)(a.y + d.y + bb.y);
    r[2] = (f16)(a.z + d.z + bb.z); r[3] = (f16)(a.w + d.w + bb.w);
    *(f16x4*)(xh + (size_t)row * HDIM + c) = r;
}

// ---------------------------------------------------------------------------
// ONE fused weight-pack kernel (verified R9/R10).
// ---------------------------------------------------------------------------
__global__ __launch_bounds__(256) void pack_all_k(
    const float* __restrict__ lin0_W,
    const float* __restrict__ W2, const float* __restrict__ W1,
    const float* __restrict__ W3,
    const float* __restrict__ Wn, const float* __restrict__ Wr,
    f16* __restrict__ dst)
{
    int idx = blockIdx.x * 256 + threadIdx.x;
    const int total = 163840 * 2 + 262144 * 3 + 524288;
    if (idx >= total) return;
    f16* d = dst + idx;
    if (idx < 327680) {
        const int half = idx / 163840;
        int r = idx % 163840;
        const int col = r / 640, k = r % 640;
        *d = (f16)lin0_W[(size_t)(k + half * 640) * 256 + col];
        return;
    }
    idx -= 327680;
    if (idx < 786432) {
        const int which = idx / 262144;
        int r = idx % 262144;
        const int i = r / 65536; r %= 65536;
        const int col = r / 256, k = r % 256;
        const float* W = (which == 0) ? W2 : (which == 1) ? W1 : W3;
        *d = (f16)W[(size_t)i * 65536 + k * 256 + col];
        return;
    }
    idx -= 786432;
    const int i = idx / 131072; int r = idx % 131072;
    const int col = r / 512, k = r % 512;
    *d = (f16)(k < 256 ? Wn[(size_t)i * 65536 + k * 256 + col]
                       : Wr[(size_t)i * 65536 + (k - 256) * 256 + col]);
}

// ---------------------------------------------------------------------------
// CSR build
// ---------------------------------------------------------------------------
__global__ __launch_bounds__(256) void count_k(
    const int* __restrict__ dstIdx, int* __restrict__ counts)
{
    const int e = blockIdx.x * 256 + threadIdx.x;
    if (e < NEDGES) atomicAdd(&counts[dstIdx[e]], 1);
}

__global__ __launch_bounds__(1024) void scan_k(
    const int* __restrict__ counts, int* __restrict__ starts)
{
    __shared__ int sm[1024];
    __shared__ int s_off;
    if (threadIdx.x == 0) s_off = 0;
    __syncthreads();
    for (int base = 0; base < NNODES; base += 1024) {
        const int i = base + threadIdx.x;
        const int v = (i < NNODES) ? counts[i] : 0;
        sm[threadIdx.x] = v;
        __syncthreads();
        for (int ofs = 1; ofs < 1024; ofs <<= 1) {
            const int t = (threadIdx.x >= ofs) ? sm[threadIdx.x - ofs] : 0;
            __syncthreads();
            sm[threadIdx.x] += t;
            __syncthreads();
        }
        const int incl = sm[threadIdx.x];
        const int off = s_off;
        if (i < NNODES) starts[i] = off + incl - v;
        __syncthreads();
        if (threadIdx.x == 1023) s_off = off + incl;
        __syncthreads();
    }
    if (threadIdx.x == 0) starts[NNODES] = s_off;
}

__global__ __launch_bounds__(256) void fillcsr_k(
    const int* __restrict__ srcIdx, const int* __restrict__ dstIdx,
    int* __restrict__ cursor, int* __restrict__ csr)
{
    const int e = blockIdx.x * 256 + threadIdx.x;
    if (e >= NEDGES) return;
    const int d = dstIdx[e];
    const int p = atomicAdd(&cursor[d], 1);
    csr[p] = srcIdx[e];
}

__global__ __launch_bounds__(256) void fill1_k(float* __restrict__ p, int n)
{
    const int t = blockIdx.x * 256 + threadIdx.x;
    if (t < n) p[t] = 1.0f;
}

// ---------------------------------------------------------------------------
extern "C" void kernel_launch(void* const* d_in, const int* in_sizes, int n_in,
                              void* d_out, int out_size, void* d_ws, size_t ws_size,
                              hipStream_t stream)
{
    const int*   edge   = (const int*)d_in[1];
    const int*   src    = edge;
    const int*   dst    = edge + NEDGES;
    const float* esm    = (const float*)d_in[2];
    const float* lin0_W = (const float*)d_in[4];
    const float* lin0_b = (const float*)d_in[5];
    const float* wc_W1  = (const float*)d_in[6];
    const float* wc_b1  = (const float*)d_in[7];
    const float* wc_W2  = (const float*)d_in[8];
    const float* wc_b2  = (const float*)d_in[9];
    const float* wc_W3  = (const float*)d_in[10];
    const float* wc_b3  = (const float*)d_in[11];
    const float* sc_Wn  = (const float*)d_in[12];
    const float* sc_bn  = (const float*)d_in[13];
    const float* sc_Wr  = (const float*)d_in[14];
    float* out = (float*)d_out;

    const size_t NH = (size_t)NNODES * HDIM;
    float* ws    = (float*)d_ws;
    float* part0 = ws;                    // f32 lin0 partial P0
    float* part1 = ws + NH;               // f32 lin0 partial P1
    f16*   xhA   = (f16*)(ws + 2 * NH);   // x ping
    f16*   xhB   = xhA + NH;              // x pong
    f16*   hnb   = xhB + NH;              // xm@W2+b2
    f16*   xw1h  = hnb + NH;              // xm@W1+b1
    f16*   maskh = xw1h + NH;             // mask
    f16*   xg    = maskh + NH;            // x*mask
    f16*   wpack = xg + NH;               // packed weights
    f16*   lin0tA = wpack;                // 163840
    f16*   lin0tB = lin0tA + 163840;      // 163840
    f16*   W2t   = lin0tB + 163840;       // 262144
    f16*   W1t   = W2t + 262144;          // 262144
    f16*   W3t   = W1t + 262144;          // 262144
    f16*   WtC   = W3t + 262144;          // 524288
    int*   iws    = (int*)(WtC + 524288);
    int*   counts = iws;
    int*   starts = iws + NNODES;
    int*   cursor = iws + 2 * NNODES + 1;
    int*   csr    = iws + 3 * NNODES + 2;

    const dim3 blk(256);
    const int gemmGrid = (NNODES + 63) / 64;           // 782
    const int edgeGrid = (NEDGES + 255) / 256;
    const int waveGrid = (NNODES * 64) / 256;          // 12500

    // ---- CSR build
    hipMemsetAsync(counts, 0, NNODES * sizeof(int), stream);
    count_k<<<edgeGrid, blk, 0, stream>>>(dst, counts);
    scan_k<<<1, 1024, 0, stream>>>(counts, starts);
    hipMemcpyAsync(cursor, starts, NNODES * sizeof(int),
                   hipMemcpyDeviceToDevice, stream);
    fillcsr_k<<<edgeGrid, blk, 0, stream>>>(src, dst, cursor, csr);

    // ---- all weight packs in ONE dispatch
    pack_all_k<<<(1638400 + 255) / 256, blk, 0, stream>>>(
        lin0_W, wc_W2, wc_W1, wc_W3, sc_Wn, sc_Wr, wpack);

    // ---- lin0 K-split, combine into xhA
    lin0_k<10><<<dim3(gemmGrid, 2), blk, 0, stream>>>(
        esm, FIN, lin0tA, lin0tB, part0, part1);
    combine_k<<<waveGrid, blk, 0, stream>>>(part0, part1, lin0_b, xhA);

    for (int i = 0; i < NLAYERS; ++i) {
        const size_t bo = (size_t)i * HDIM;
        const f16* w2 = W2t + i * 65536;
        const f16* w1 = W1t + i * 65536;
        const f16* w3 = W3t + i * 65536;
        const f16* wc = WtC + i * 131072;
        const f16* xcur = (i & 1) ? xhB : xhA;
        f16*       xnew = (i & 1) ? xhA : xhB;

        // W2|W1 pair: y0 -> hnb = f16(xm@W2+b2); y1 -> xw1h = f16(xm@W1+b1)
        if (i == 0) {
            w2w1_k<SRC_H><<<dim3(gemmGrid, 2), blk, 0, stream>>>(
                xcur, nullptr, w2, w1, wc_b2 + bo, wc_b1 + bo, hnb, xw1h);
        } else {
            w2w1_k<SRC_MULH><<<dim3(gemmGrid, 2), blk, 0, stream>>>(
                xcur, maskh, w2, w1, wc_b2 + bo, wc_b1 + bo, hnb, xw1h);
        }
        // fused gather1 + mask GEMM: maskh, xg
        g1m_k<<<gemmGrid, blk, 0, stream>>>(
            hnb, csr, starts, xw1h, xcur, w3, wc_b3 + bo, maskh, xg);
        // fused gather2 + CATH GEMM: out slice + xnew
        g2c_k<<<gemmGrid, blk, 0, stream>>>(
            xg, csr, starts, xcur, wc, sc_bn + bo,
            out + (size_t)i * HDIM, xnew);
    }

    // node_mask: all true
    const size_t maskOff = (size_t)NNODES * LDOUT;
    fill1_k<<<(NNODES + 255) / 256, blk, 0, stream>>>(out + maskOff, NNODES);
}

// Round 12
// 1353.046 us; speedup vs baseline: 1.4291x; 1.4291x over previous
//
#include <hip/hip_runtime.h>

#define NNODES 50000
#define HDIM 256
#define NLAYERS 4
#define NEDGES 800000
#define FIN 1280
#define LDOUT 1024

typedef _Float16 f16;
typedef __attribute__((ext_vector_type(8))) _Float16 f16x8;
typedef __attribute__((ext_vector_type(4))) _Float16 f16x4;
typedef __attribute__((ext_vector_type(4))) float f32x4;

enum { SRC_H = 0, SRC_CATH = 1 };
enum { EPI_HRELU = 0, EPI_MASKXG = 1, EPI_CATH2 = 2 };

// ---------------------------------------------------------------------------
// Layer MFMA GEMM (R10-verified structure): BM=64 x BN=256, BK=64,
// 256 thr = 4 waves; double-buffered LDS A-tile + depth-2 reg prefetch.
// SRC_H: A = A3 [N,256].  SRC_CATH: A = [A3 | A4] (K=512).
// EPI_HRELU : h   = relu(v + deg[row]*bias + bias2)        -> Ch
// EPI_MASKXG: m   = sigmoid(v + bias); Ch2=m; Ch = Xh*m
// EPI_CATH2 : r   = relu(v + bias); Cf=r (ld ldc); Ch=r; Ch3 = r*Xh  (xm')
// RACE RULE: in-place xh (A4==Ch) is safe: gridDim.y==1, block reads only
// its own 64 rows, epilogue strictly after K-loop (R10-validated).
// MFMA layouts refcheck-validated R3-R11: A row=l&15, k=(l>>4)*8+j (+32kb);
// B col=l&15 (col-major Wt); C/D col=l&15, row=(l>>4)*4+reg.
// ---------------------------------------------------------------------------
template<int SRC, int EPI, int KTILES>
__global__ __launch_bounds__(256) void mgemm_k(
    const f16*  __restrict__ A3,      // aggx / h / agg2
    const f16*  __restrict__ A4,      // xm / xh (CATH, k>=256)
    const f16*  __restrict__ Xh,      // xh (MASKXG) / maskh (CATH2)
    const int*  __restrict__ deg,     // counts (HRELU)
    const f16*  __restrict__ Wt,      // [256 cols][K] col-major f16
    const float* __restrict__ bias,
    const float* __restrict__ bias2,
    float* __restrict__ Cf, int ldc,
    f16*  __restrict__ Ch,
    f16*  __restrict__ Ch2,
    f16*  __restrict__ Ch3)
{
    constexpr int K = KTILES * 64;
    __shared__ f16 Asm[2][4096];      // 2 x 8 KB

    const int row0 = blockIdx.x * 64;
    const int tid = threadIdx.x;
    const int wv = tid >> 6;
    const int l = tid & 63;

    f32x4 acc[4][4] = {};

    const int sr = tid >> 2;
    const int sc0 = (tid & 3) * 16;
    const int grow = row0 + sr;
    const bool rok = grow < NNODES;
    const int lane_base0 =
        (((sc0 >> 5) * 4 + (sr >> 4)) * 64 + (sr & 15) + (((sc0 & 31) >> 3) * 16)) * 8;
    const int lane_base1 = lane_base0 + 128;

    const f16* bp[4];
    #pragma unroll
    for (int cf = 0; cf < 4; ++cf)
        bp[cf] = Wt + (size_t)(wv * 64 + cf * 16 + (l & 15)) * K + ((l >> 4) * 8);

    struct SReg { f16x8 h0, h1; };
    SReg RA, RB;

    auto LOAD = [&](SReg& r, int kt) {
        if (!rok) return;
        const int k0 = kt * 64 + sc0;
        const f16* p;
        if constexpr (SRC == SRC_CATH) {
            p = (k0 < HDIM) ? (A3 + (size_t)grow * HDIM + k0)
                            : (A4 + (size_t)grow * HDIM + (k0 - HDIM));
        } else {
            p = A3 + (size_t)grow * HDIM + k0;
        }
        r.h0 = *(const f16x8*)p;  r.h1 = *(const f16x8*)(p + 8);
    };

    auto COMMIT = [&](const SReg& r, int b) {
        f16x8 av0, av1;
        #pragma unroll
        for (int i = 0; i < 8; ++i) { av0[i] = (f16)0.f; av1[i] = (f16)0.f; }
        if (rok) { av0 = r.h0; av1 = r.h1; }
        *(f16x8*)(&Asm[b][lane_base0]) = av0;
        *(f16x8*)(&Asm[b][lane_base1]) = av1;
    };

    auto TILE = [&](int b, int kt) {
        f16x8 af[4][2];
        #pragma unroll
        for (int rf = 0; rf < 4; ++rf)
            #pragma unroll
            for (int kb = 0; kb < 2; ++kb)
                af[rf][kb] = *(const f16x8*)(&Asm[b][((kb * 4 + rf) * 64 + l) * 8]);
        f16x8 bfr[4][2];
        #pragma unroll
        for (int cf = 0; cf < 4; ++cf) {
            bfr[cf][0] = *(const f16x8*)(bp[cf] + kt * 64);
            bfr[cf][1] = *(const f16x8*)(bp[cf] + kt * 64 + 32);
        }
        #pragma unroll
        for (int cf = 0; cf < 4; ++cf)
            #pragma unroll
            for (int rf = 0; rf < 4; ++rf)
                #pragma unroll
                for (int kb = 0; kb < 2; ++kb)
                    acc[rf][cf] = __builtin_amdgcn_mfma_f32_16x16x32_f16(
                        af[rf][kb], bfr[cf][kb], acc[rf][cf], 0, 0, 0);
    };

    LOAD(RA, 0);
    COMMIT(RA, 0);
    if (KTILES > 1) LOAD(RB, 1);
    #pragma unroll
    for (int kt2 = 0; kt2 < KTILES; kt2 += 2) {
        __syncthreads();
        TILE(0, kt2);
        if (kt2 + 1 < KTILES) COMMIT(RB, 1);
        if (kt2 + 2 < KTILES) LOAD(RA, kt2 + 2);
        if (kt2 + 1 < KTILES) {
            __syncthreads();
            TILE(1, kt2 + 1);
            if (kt2 + 2 < KTILES) COMMIT(RA, 0);
            if (kt2 + 3 < KTILES) LOAD(RB, kt2 + 3);
        }
    }

    // ---- epilogue
    #pragma unroll
    for (int rf = 0; rf < 4; ++rf) {
        #pragma unroll
        for (int j = 0; j < 4; ++j) {
            const int row = row0 + rf * 16 + ((l >> 4) * 4) + j;
            if (row >= NNODES) continue;
            #pragma unroll
            for (int cf = 0; cf < 4; ++cf) {
                const int col = wv * 64 + cf * 16 + (l & 15);
                float v = acc[rf][cf][j];
                if constexpr (EPI == EPI_HRELU) {
                    const float dv = (float)deg[row];
                    v = fmaxf(v + dv * bias[col] + bias2[col], 0.f);
                    Ch[(size_t)row * HDIM + col] = (f16)v;
                } else if constexpr (EPI == EPI_MASKXG) {
                    const float m = 1.f / (1.f + expf(-(v + bias[col])));
                    Ch2[(size_t)row * HDIM + col] = (f16)m;
                    Ch[(size_t)row * HDIM + col] =
                        (f16)((float)Xh[(size_t)row * HDIM + col] * m);
                } else { // EPI_CATH2
                    const float r = fmaxf(v + bias[col], 0.f);
                    Cf[(size_t)row * ldc + col] = r;
                    Ch[(size_t)row * HDIM + col] = (f16)r;
                    Ch3[(size_t)row * HDIM + col] =
                        (f16)(r * (float)Xh[(size_t)row * HDIM + col]);
                }
            }
        }
    }
}

// ---------------------------------------------------------------------------
// lin0 GEMM: R7-R10 structure, K-split x4 via blockIdx.y (KTILES=5, K=320).
// Partials written f16 (halved write traffic).
// ---------------------------------------------------------------------------
template<int KTILES>
__global__ __launch_bounds__(256) void lin0_k(
    const float* __restrict__ A1, int lda1,
    const f16*  __restrict__ WtBase,   // 4 slices of [256][320]
    f16* __restrict__ parts)           // 4 x N*256 f16
{
    constexpr int K = KTILES * 64;     // 320
    __shared__ f16 Asm[2][4096];

    const int row0 = blockIdx.x * 64;
    const int by = blockIdx.y;
    const int tid = threadIdx.x;
    const int wv = tid >> 6;
    const int l = tid & 63;

    f32x4 acc[4][4] = {};

    const int sr = tid >> 2;
    const int sc0 = (tid & 3) * 16;
    const int grow = row0 + sr;
    const bool rok = grow < NNODES;
    const int kg = by * K;
    const int lane_base0 =
        (((sc0 >> 5) * 4 + (sr >> 4)) * 64 + (sr & 15) + (((sc0 & 31) >> 3) * 16)) * 8;
    const int lane_base1 = lane_base0 + 128;

    const f16* Wsel = WtBase + (size_t)by * 256 * K;
    const f16* bp[4];
    #pragma unroll
    for (int cf = 0; cf < 4; ++cf)
        bp[cf] = Wsel + (size_t)(wv * 64 + cf * 16 + (l & 15)) * K + ((l >> 4) * 8);

    struct SReg { float4 f0, f1, f2, f3; };
    SReg RA, RB;

    auto LOAD = [&](SReg& r, int kt) {
        if (!rok) return;
        const float* p = A1 + (size_t)grow * lda1 + kg + kt * 64 + sc0;
        r.f0 = *(const float4*)(p + 0);  r.f1 = *(const float4*)(p + 4);
        r.f2 = *(const float4*)(p + 8);  r.f3 = *(const float4*)(p + 12);
    };

    auto COMMIT = [&](const SReg& r, int b) {
        f16x8 av0, av1;
        #pragma unroll
        for (int i = 0; i < 8; ++i) { av0[i] = (f16)0.f; av1[i] = (f16)0.f; }
        if (rok) {
            av0[0]=(f16)r.f0.x; av0[1]=(f16)r.f0.y; av0[2]=(f16)r.f0.z; av0[3]=(f16)r.f0.w;
            av0[4]=(f16)r.f1.x; av0[5]=(f16)r.f1.y; av0[6]=(f16)r.f1.z; av0[7]=(f16)r.f1.w;
            av1[0]=(f16)r.f2.x; av1[1]=(f16)r.f2.y; av1[2]=(f16)r.f2.z; av1[3]=(f16)r.f2.w;
            av1[4]=(f16)r.f3.x; av1[5]=(f16)r.f3.y; av1[6]=(f16)r.f3.z; av1[7]=(f16)r.f3.w;
        }
        *(f16x8*)(&Asm[b][lane_base0]) = av0;
        *(f16x8*)(&Asm[b][lane_base1]) = av1;
    };

    auto TILE = [&](int b, int kt) {
        f16x8 af[4][2];
        #pragma unroll
        for (int rf = 0; rf < 4; ++rf)
            #pragma unroll
            for (int kb = 0; kb < 2; ++kb)
                af[rf][kb] = *(const f16x8*)(&Asm[b][((kb * 4 + rf) * 64 + l) * 8]);
        f16x8 bfr[4][2];
        #pragma unroll
        for (int cf = 0; cf < 4; ++cf) {
            bfr[cf][0] = *(const f16x8*)(bp[cf] + kt * 64);
            bfr[cf][1] = *(const f16x8*)(bp[cf] + kt * 64 + 32);
        }
        #pragma unroll
        for (int cf = 0; cf < 4; ++cf)
            #pragma unroll
            for (int rf = 0; rf < 4; ++rf)
                #pragma unroll
                for (int kb = 0; kb < 2; ++kb)
                    acc[rf][cf] = __builtin_amdgcn_mfma_f32_16x16x32_f16(
                        af[rf][kb], bfr[cf][kb], acc[rf][cf], 0, 0, 0);
    };

    LOAD(RA, 0);
    COMMIT(RA, 0);
    if (KTILES > 1) LOAD(RB, 1);
    #pragma unroll
    for (int kt2 = 0; kt2 < KTILES; kt2 += 2) {
        __syncthreads();
        TILE(0, kt2);
        if (kt2 + 1 < KTILES) COMMIT(RB, 1);
        if (kt2 + 2 < KTILES) LOAD(RA, kt2 + 2);
        if (kt2 + 1 < KTILES) {
            __syncthreads();
            TILE(1, kt2 + 1);
            if (kt2 + 2 < KTILES) COMMIT(RA, 0);
            if (kt2 + 3 < KTILES) LOAD(RB, kt2 + 3);
        }
    }

    f16* Ph = parts + (size_t)by * NNODES * HDIM;
    #pragma unroll
    for (int rf = 0; rf < 4; ++rf) {
        #pragma unroll
        for (int j = 0; j < 4; ++j) {
            const int row = row0 + rf * 16 + ((l >> 4) * 4) + j;
            if (row >= NNODES) continue;
            #pragma unroll
            for (int cf = 0; cf < 4; ++cf) {
                const int col = wv * 64 + cf * 16 + (l & 15);
                Ph[(size_t)row * HDIM + col] = (f16)acc[rf][cf][j];
            }
        }
    }
}

// ---------------------------------------------------------------------------
// combine4: xh = f16(p0+p1+p2+p3 + b)
// ---------------------------------------------------------------------------
__global__ __launch_bounds__(256) void combine4_k(
    const f16* __restrict__ parts, const float* __restrict__ b,
    f16* __restrict__ xh)
{
    const int t = blockIdx.x * 256 + threadIdx.x;
    const int row = t >> 6;
    const int c = (t & 63) * 4;
    if (row >= NNODES) return;
    const size_t NH = (size_t)NNODES * HDIM;
    const size_t off = (size_t)row * HDIM + c;
    f16x4 p0 = *(const f16x4*)(parts + off);
    f16x4 p1 = *(const f16x4*)(parts + NH + off);
    f16x4 p2 = *(const f16x4*)(parts + 2 * NH + off);
    f16x4 p3 = *(const f16x4*)(parts + 3 * NH + off);
    const float4 bb = *(const float4*)(b + c);
    f16x4 r;
    r[0] = (f16)((float)p0[0] + (float)p1[0] + (float)p2[0] + (float)p3[0] + bb.x);
    r[1] = (f16)((float)p0[1] + (float)p1[1] + (float)p2[1] + (float)p3[1] + bb.y);
    r[2] = (f16)((float)p0[2] + (float)p1[2] + (float)p2[2] + (float)p3[2] + bb.z);
    r[3] = (f16)((float)p0[3] + (float)p1[3] + (float)p2[3] + (float)p3[3] + bb.w);
    *(f16x4*)(xh + off) = r;
}

// ---------------------------------------------------------------------------
// ONE fused weight-pack kernel.
// dst layout (f16): [lin0 4x(256x320) = 327680][WH 4x(256x512) = 524288]
//                   [W3t 4x65536 = 262144][WtC 4x131072 = 524288]
// WH: [W2;W1] concat over K (k<256 -> W2, else W1), col-major.
// ---------------------------------------------------------------------------
__global__ __launch_bounds__(256) void pack_all_k(
    const float* __restrict__ lin0_W,
    const float* __restrict__ W2, const float* __restrict__ W1,
    const float* __restrict__ W3,
    const float* __restrict__ Wn, const float* __restrict__ Wr,
    f16* __restrict__ dst)
{
    int idx = blockIdx.x * 256 + threadIdx.x;
    const int total = 327680 + 524288 + 262144 + 524288;
    if (idx >= total) return;
    f16* d = dst + idx;
    if (idx < 327680) {                       // lin0 K-quarter slices
        const int q = idx / 81920;
        int r = idx % 81920;
        const int col = r / 320, k = r % 320;
        *d = (f16)lin0_W[(size_t)(k + q * 320) * 256 + col];
        return;
    }
    idx -= 327680;
    if (idx < 524288) {                       // WH = [W2;W1]
        const int i = idx / 131072;
        int r = idx % 131072;
        const int col = r / 512, k = r % 512;
        *d = (f16)(k < 256 ? W2[(size_t)i * 65536 + k * 256 + col]
                           : W1[(size_t)i * 65536 + (k - 256) * 256 + col]);
        return;
    }
    idx -= 524288;
    if (idx < 262144) {                       // W3t
        const int i = idx / 65536;
        int r = idx % 65536;
        const int col = r / 256, k = r % 256;
        *d = (f16)W3[(size_t)i * 65536 + k * 256 + col];
        return;
    }
    idx -= 262144;                            // WtC = [Wn;Wr]
    const int i = idx / 131072; int r = idx % 131072;
    const int col = r / 512, k = r % 512;
    *d = (f16)(k < 256 ? Wn[(size_t)i * 65536 + k * 256 + col]
                       : Wr[(size_t)i * 65536 + (k - 256) * 256 + col]);
}

// ---------------------------------------------------------------------------
// CSR build (counts doubles as degree table for EPI_HRELU)
// ---------------------------------------------------------------------------
__global__ __launch_bounds__(256) void count_k(
    const int* __restrict__ dstIdx, int* __restrict__ counts)
{
    const int e = blockIdx.x * 256 + threadIdx.x;
    if (e < NEDGES) atomicAdd(&counts[dstIdx[e]], 1);
}

__global__ __launch_bounds__(1024) void scan_k(
    const int* __restrict__ counts, int* __restrict__ starts)
{
    __shared__ int sm[1024];
    __shared__ int s_off;
    if (threadIdx.x == 0) s_off = 0;
    __syncthreads();
    for (int base = 0; base < NNODES; base += 1024) {
        const int i = base + threadIdx.x;
        const int v = (i < NNODES) ? counts[i] : 0;
        sm[threadIdx.x] = v;
        __syncthreads();
        for (int ofs = 1; ofs < 1024; ofs <<= 1) {
            const int t = (threadIdx.x >= ofs) ? sm[threadIdx.x - ofs] : 0;
            __syncthreads();
            sm[threadIdx.x] += t;
            __syncthreads();
        }
        const int incl = sm[threadIdx.x];
        const int off = s_off;
        if (i < NNODES) starts[i] = off + incl - v;
        __syncthreads();
        if (threadIdx.x == 1023) s_off = off + incl;
        __syncthreads();
    }
    if (threadIdx.x == 0) starts[NNODES] = s_off;
}

__global__ __launch_bounds__(256) void fillcsr_k(
    const int* __restrict__ srcIdx, const int* __restrict__ dstIdx,
    int* __restrict__ cursor, int* __restrict__ csr)
{
    const int e = blockIdx.x * 256 + threadIdx.x;
    if (e >= NEDGES) return;
    const int d = dstIdx[e];
    const int p = atomicAdd(&cursor[d], 1);
    csr[p] = srcIdx[e];
}

// ---------------------------------------------------------------------------
// gather-sum (R10-verified): one wave per node, f16 rows, f32 accum, unroll-4
// ---------------------------------------------------------------------------
__global__ __launch_bounds__(256) void gather_g_k(
    const f16* __restrict__ rows, const int* __restrict__ csr,
    const int* __restrict__ starts, f16* __restrict__ outp)
{
    const int node = (blockIdx.x * 256 + threadIdx.x) >> 6;
    const int lane = threadIdx.x & 63;
    if (node >= NNODES) return;
    const int e0 = starts[node], e1 = starts[node + 1];
    float a0=0,a1=0,a2=0,a3=0, b0=0,b1=0,b2=0,b3=0;
    int e = e0;
    for (; e + 3 < e1; e += 4) {
        const int s0=csr[e], s1=csr[e+1], s2=csr[e+2], s3=csr[e+3];
        f16x4 v0 = *(const f16x4*)(rows + (size_t)s0 * HDIM + lane * 4);
        f16x4 v1 = *(const f16x4*)(rows + (size_t)s1 * HDIM + lane * 4);
        f16x4 v2 = *(const f16x4*)(rows + (size_t)s2 * HDIM + lane * 4);
        f16x4 v3 = *(const f16x4*)(rows + (size_t)s3 * HDIM + lane * 4);
        a0 += (float)v0[0] + (float)v2[0]; a1 += (float)v0[1] + (float)v2[1];
        a2 += (float)v0[2] + (float)v2[2]; a3 += (float)v0[3] + (float)v2[3];
        b0 += (float)v1[0] + (float)v3[0]; b1 += (float)v1[1] + (float)v3[1];
        b2 += (float)v1[2] + (float)v3[2]; b3 += (float)v1[3] + (float)v3[3];
    }
    for (; e < e1; ++e) {
        const int s0 = csr[e];
        f16x4 v0 = *(const f16x4*)(rows + (size_t)s0 * HDIM + lane * 4);
        a0 += (float)v0[0]; a1 += (float)v0[1]; a2 += (float)v0[2]; a3 += (float)v0[3];
    }
    f16x4 r;
    r[0] = (f16)(a0 + b0); r[1] = (f16)(a1 + b1);
    r[2] = (f16)(a2 + b2); r[3] = (f16)(a3 + b3);
    *(f16x4*)(outp + (size_t)node * HDIM + lane * 4) = r;
}

__global__ __launch_bounds__(256) void fill1_k(float* __restrict__ p, int n)
{
    const int t = blockIdx.x * 256 + threadIdx.x;
    if (t < n) p[t] = 1.0f;
}

// ---------------------------------------------------------------------------
extern "C" void kernel_launch(void* const* d_in, const int* in_sizes, int n_in,
                              void* d_out, int out_size, void* d_ws, size_t ws_size,
                              hipStream_t stream)
{
    const int*   edge   = (const int*)d_in[1];
    const int*   src    = edge;
    const int*   dst    = edge + NEDGES;
    const float* esm    = (const float*)d_in[2];
    const float* lin0_W = (const float*)d_in[4];
    const float* lin0_b = (const float*)d_in[5];
    const float* wc_W1  = (const float*)d_in[6];
    const float* wc_b1  = (const float*)d_in[7];
    const float* wc_W2  = (const float*)d_in[8];
    const float* wc_b2  = (const float*)d_in[9];
    const float* wc_W3  = (const float*)d_in[10];
    const float* wc_b3  = (const float*)d_in[11];
    const float* sc_Wn  = (const float*)d_in[12];
    const float* sc_bn  = (const float*)d_in[13];
    const float* sc_Wr  = (const float*)d_in[14];
    float* out = (float*)d_out;

    const size_t NH = (size_t)NNODES * HDIM;
    f16* parts = (f16*)d_ws;              // 4 x NH (lin0 partials; then reused:
    f16* aggx  = parts;                   //   p0 -> aggx
    f16* hbuf  = parts + NH;              //   p1 -> h
    f16* xg    = parts + 2 * NH;          //   p2 -> xg
    f16* agg2  = parts + 3 * NH;          //   p3 -> agg2
    f16* xh    = parts + 4 * NH;          // persistent x
    f16* xm    = xh + NH;                 // persistent x*mask table
    f16* maskh = xm + NH;                 // persistent mask
    f16* wpack = maskh + NH;
    f16* lin0t = wpack;                   // 327680
    f16* WH    = lin0t + 327680;          // 524288
    f16* W3t   = WH + 524288;             // 262144
    f16* WtC   = W3t + 262144;            // 524288
    int* iws    = (int*)(WtC + 524288);
    int* counts = iws;                    // degree table (kept!)
    int* starts = iws + NNODES;
    int* cursor = iws + 2 * NNODES + 1;
    int* csr    = iws + 3 * NNODES + 2;

    const dim3 blk(256);
    const int gemmGrid = (NNODES + 63) / 64;           // 782
    const int edgeGrid = (NEDGES + 255) / 256;
    const int waveGrid = (NNODES * 64) / 256;          // 12500

    // ---- CSR build (counts survives as degree table)
    hipMemsetAsync(counts, 0, NNODES * sizeof(int), stream);
    count_k<<<edgeGrid, blk, 0, stream>>>(dst, counts);
    scan_k<<<1, 1024, 0, stream>>>(counts, starts);
    hipMemcpyAsync(cursor, starts, NNODES * sizeof(int),
                   hipMemcpyDeviceToDevice, stream);
    fillcsr_k<<<edgeGrid, blk, 0, stream>>>(src, dst, cursor, csr);

    // ---- all weight packs in ONE dispatch
    pack_all_k<<<(1638400 + 255) / 256, blk, 0, stream>>>(
        lin0_W, wc_W2, wc_W1, wc_W3, sc_Wn, sc_Wr, wpack);

    // ---- lin0 K-split x4 -> f16 partials -> combine into xh
    lin0_k<5><<<dim3(gemmGrid, 4), blk, 0, stream>>>(esm, FIN, lin0t, parts);
    combine4_k<<<waveGrid, blk, 0, stream>>>(parts, lin0_b, xh);

    for (int i = 0; i < NLAYERS; ++i) {
        const size_t bo = (size_t)i * HDIM;
        const f16* wh = WH + (size_t)i * 131072;
        const f16* w3 = W3t + (size_t)i * 65536;
        const f16* wc = WtC + (size_t)i * 131072;
        const f16* xmtab = (i == 0) ? xh : xm;   // layer 0: mask is None

        // aggx = segment_sum(xm[src], dst)
        gather_g_k<<<waveGrid, blk, 0, stream>>>(xmtab, csr, starts, aggx);
        // h = relu([aggx|xm]@[W2;W1] + deg*b2 + b1)     (linearity reorg)
        mgemm_k<SRC_CATH, EPI_HRELU, 8><<<gemmGrid, blk, 0, stream>>>(
            aggx, xmtab, nullptr, counts, wh, wc_b2 + bo, wc_b1 + bo,
            nullptr, 0, hbuf, nullptr, nullptr);
        // mask = sigmoid(h@W3 + b3); xg = xh*mask
        mgemm_k<SRC_H, EPI_MASKXG, 4><<<gemmGrid, blk, 0, stream>>>(
            hbuf, nullptr, xh, nullptr, w3, wc_b3 + bo, nullptr,
            nullptr, 0, xg, maskh, nullptr);
        // agg2 = segment_sum(xg[src], dst)
        gather_g_k<<<waveGrid, blk, 0, stream>>>(xg, csr, starts, agg2);
        // x' = relu([agg2|xh]@[Wn;Wr] + bn) -> out slice, xh (in-place, R10-
        // validated), and xm' = x'*mask for next layer's gather
        mgemm_k<SRC_CATH, EPI_CATH2, 8><<<gemmGrid, blk, 0, stream>>>(
            agg2, xh, maskh, nullptr, wc, sc_bn + bo, nullptr,
            out + (size_t)i * HDIM, LDOUT, xh, nullptr, xm);
    }

    // node_mask: all true
    const size_t maskOff = (size_t)NNODES * LDOUT;
    fill1_k<<<(NNODES + 255) / 256, blk, 0, stream>>>(out + maskOff, NNODES);
}

// Round 13
// 1312.489 us; speedup vs baseline: 1.4732x; 1.0309x over previous
//
#include <hip/hip_runtime.h>

#define NNODES 50000
#define HDIM 256
#define NLAYERS 4
#define NEDGES 800000
#define FIN 1280
#define LDOUT 1024

typedef _Float16 f16;
typedef __attribute__((ext_vector_type(8))) _Float16 f16x8;
typedef __attribute__((ext_vector_type(4))) _Float16 f16x4;
typedef __attribute__((ext_vector_type(4))) float f32x4;

// ---------------------------------------------------------------------------
// Frag-major LDS layout for a 64row x 256col f16 panel (32 KB), R11-verified:
//   (row,col) -> idx = (( (col>>6)*8 + ((col>>5)&1)*4 + (row>>4) )*64
//                       + ((col>>3)&3)*16 + (row&15))*8 + (col&7)
// Read side (A-frag, tile kt, kb, rf, lane l, 8 f16):
//   &lds[((kt*8 + kb*4 + rf)*64 + l)*8]
// MFMA layouts refcheck-validated R3-R12: A row=l&15, k=(l>>4)*8+j (+32kb);
// B col=l&15 (col-major Wt); C/D col=l&15, row=(l>>4)*4+reg.
// ---------------------------------------------------------------------------

// ---------------------------------------------------------------------------
// Fused h + mask GEMM (hm_k):
// phase A: h = relu([aggx|xm]@[W2;W1] + deg*b2 + b1)  (K=512, R12 template),
//          epilogue -> frag-major LDS (no global h)
// phase B: mask = sigmoid(h@W3 + b3) (K=256, A from LDS, barrier-free)
// epilogue B: maskh = m; xg = xh*m
// LDS overlay: Asm dbuf (16 KB) occupies lds[0..8191] during phase A; after
// the last TILE + barrier, all 32 KB become the Hfr panel.
// ---------------------------------------------------------------------------
__global__ __launch_bounds__(256) void hm_k(
    const f16*  __restrict__ aggx,
    const f16*  __restrict__ xm,
    const f16*  __restrict__ xh,
    const int*  __restrict__ deg,
    const f16*  __restrict__ WH,      // [256][512] col-major
    const f16*  __restrict__ W3t,     // [256][256] col-major
    const float* __restrict__ b2,
    const float* __restrict__ b1,
    const float* __restrict__ b3,
    f16* __restrict__ maskh,
    f16* __restrict__ xg)
{
    __shared__ f16 lds[16384];        // 32 KB: phase A dbuf overlay + Hfr

    const int row0 = blockIdx.x * 64;
    const int tid = threadIdx.x;
    const int wv = tid >> 6;
    const int l = tid & 63;

    // ------------- phase A: K=512 GEMM over [aggx | xm] -------------
    f32x4 acc[4][4] = {};

    const int sr = tid >> 2;
    const int sc0 = (tid & 3) * 16;
    const int grow = row0 + sr;
    const bool rok = grow < NNODES;
    const int lane_base0 =
        (((sc0 >> 5) * 4 + (sr >> 4)) * 64 + (sr & 15) + (((sc0 & 31) >> 3) * 16)) * 8;
    const int lane_base1 = lane_base0 + 128;

    const f16* bp[4];
    #pragma unroll
    for (int cf = 0; cf < 4; ++cf)
        bp[cf] = WH + (size_t)(wv * 64 + cf * 16 + (l & 15)) * 512 + ((l >> 4) * 8);

    struct SReg { f16x8 h0, h1; };
    SReg RA, RB;

    auto LOAD = [&](SReg& r, int kt) {
        if (!rok) return;
        const int k0 = kt * 64 + sc0;
        const f16* p = (k0 < HDIM) ? (aggx + (size_t)grow * HDIM + k0)
                                   : (xm + (size_t)grow * HDIM + (k0 - HDIM));
        r.h0 = *(const f16x8*)p;  r.h1 = *(const f16x8*)(p + 8);
    };

    auto COMMIT = [&](const SReg& r, int b) {
        f16x8 av0, av1;
        #pragma unroll
        for (int i = 0; i < 8; ++i) { av0[i] = (f16)0.f; av1[i] = (f16)0.f; }
        if (rok) { av0 = r.h0; av1 = r.h1; }
        *(f16x8*)(&lds[b * 4096 + lane_base0]) = av0;
        *(f16x8*)(&lds[b * 4096 + lane_base1]) = av1;
    };

    auto TILE = [&](int b, int kt) {
        f16x8 af[4][2];
        #pragma unroll
        for (int rf = 0; rf < 4; ++rf)
            #pragma unroll
            for (int kb = 0; kb < 2; ++kb)
                af[rf][kb] = *(const f16x8*)(&lds[b * 4096 + ((kb * 4 + rf) * 64 + l) * 8]);
        f16x8 bfr[4][2];
        #pragma unroll
        for (int cf = 0; cf < 4; ++cf) {
            bfr[cf][0] = *(const f16x8*)(bp[cf] + kt * 64);
            bfr[cf][1] = *(const f16x8*)(bp[cf] + kt * 64 + 32);
        }
        #pragma unroll
        for (int cf = 0; cf < 4; ++cf)
            #pragma unroll
            for (int rf = 0; rf < 4; ++rf)
                #pragma unroll
                for (int kb = 0; kb < 2; ++kb)
                    acc[rf][cf] = __builtin_amdgcn_mfma_f32_16x16x32_f16(
                        af[rf][kb], bfr[cf][kb], acc[rf][cf], 0, 0, 0);
    };

    LOAD(RA, 0);
    COMMIT(RA, 0);
    LOAD(RB, 1);
    #pragma unroll
    for (int kt2 = 0; kt2 < 8; kt2 += 2) {
        __syncthreads();
        TILE(0, kt2);
        COMMIT(RB, 1);
        if (kt2 + 2 < 8) LOAD(RA, kt2 + 2);
        __syncthreads();
        TILE(1, kt2 + 1);
        if (kt2 + 2 < 8) COMMIT(RA, 0);
        if (kt2 + 3 < 8) LOAD(RB, kt2 + 3);
    }
    __syncthreads();                  // all reads of Asm done -> reuse as Hfr

    // epilogue A: h -> frag-major LDS
    #pragma unroll
    for (int rf = 0; rf < 4; ++rf) {
        #pragma unroll
        for (int j = 0; j < 4; ++j) {
            const int rowl = rf * 16 + ((l >> 4) * 4) + j;
            const int row = row0 + rowl;
            const float dv = (row < NNODES) ? (float)deg[row] : 0.f;
            #pragma unroll
            for (int cf = 0; cf < 4; ++cf) {
                const int col = wv * 64 + cf * 16 + (l & 15);
                const float h = fmaxf(acc[rf][cf][j] + dv * b2[col] + b1[col], 0.f);
                const int idx =
                    (((col >> 6) * 8 + ((col >> 5) & 1) * 4 + (rowl >> 4)) * 64
                     + ((col >> 3) & 3) * 16 + (rowl & 15)) * 8 + (col & 7);
                lds[idx] = (f16)h;
            }
        }
    }
    __syncthreads();

    // ------------- phase B: mask GEMM (A = Hfr, K=256) -------------
    const f16* bp3[4];
    #pragma unroll
    for (int cf = 0; cf < 4; ++cf)
        bp3[cf] = W3t + (size_t)(wv * 64 + cf * 16 + (l & 15)) * 256 + ((l >> 4) * 8);

    f32x4 acc2[4][4] = {};
    f16x8 bC[4][2], bN[4][2];
    #pragma unroll
    for (int cf = 0; cf < 4; ++cf) {
        bC[cf][0] = *(const f16x8*)(bp3[cf]);
        bC[cf][1] = *(const f16x8*)(bp3[cf] + 32);
    }
    #pragma unroll
    for (int kt = 0; kt < 4; ++kt) {
        if (kt < 3) {
            #pragma unroll
            for (int cf = 0; cf < 4; ++cf) {
                bN[cf][0] = *(const f16x8*)(bp3[cf] + (kt + 1) * 64);
                bN[cf][1] = *(const f16x8*)(bp3[cf] + (kt + 1) * 64 + 32);
            }
        }
        f16x8 af[4][2];
        #pragma unroll
        for (int rf = 0; rf < 4; ++rf)
            #pragma unroll
            for (int kb = 0; kb < 2; ++kb)
                af[rf][kb] = *(const f16x8*)(&lds[((kt * 8 + kb * 4 + rf) * 64 + l) * 8]);
        #pragma unroll
        for (int cf = 0; cf < 4; ++cf)
            #pragma unroll
            for (int rf = 0; rf < 4; ++rf)
                #pragma unroll
                for (int kb = 0; kb < 2; ++kb)
                    acc2[rf][cf] = __builtin_amdgcn_mfma_f32_16x16x32_f16(
                        af[rf][kb], bC[cf][kb], acc2[rf][cf], 0, 0, 0);
        if (kt < 3) {
            #pragma unroll
            for (int cf = 0; cf < 4; ++cf) {
                bC[cf][0] = bN[cf][0];  bC[cf][1] = bN[cf][1];
            }
        }
    }

    // epilogue B: mask + xg
    #pragma unroll
    for (int rf = 0; rf < 4; ++rf) {
        #pragma unroll
        for (int j = 0; j < 4; ++j) {
            const int row = row0 + rf * 16 + ((l >> 4) * 4) + j;
            if (row >= NNODES) continue;
            #pragma unroll
            for (int cf = 0; cf < 4; ++cf) {
                const int col = wv * 64 + cf * 16 + (l & 15);
                const float m = 1.f / (1.f + expf(-(acc2[rf][cf][j] + b3[col])));
                maskh[(size_t)row * HDIM + col] = (f16)m;
                xg[(size_t)row * HDIM + col] =
                    (f16)((float)xh[(size_t)row * HDIM + col] * m);
            }
        }
    }
}

// ---------------------------------------------------------------------------
// CATH2 GEMM (R12-verified): x' = relu([agg2|xh]@[Wn;Wr] + bn)
// -> out (f32 ld 1024), xh (f16, in-place safe), xm' = x'*mask
// ---------------------------------------------------------------------------
__global__ __launch_bounds__(256) void cath2_k(
    const f16*  __restrict__ A3,      // agg2
    const f16*  __restrict__ A4,      // xh (k>=256)
    const f16*  __restrict__ Mh,      // maskh
    const f16*  __restrict__ Wt,      // [256][512] col-major
    const float* __restrict__ bias,
    float* __restrict__ Cf, int ldc,
    f16*  __restrict__ Ch,            // xh (in-place)
    f16*  __restrict__ Ch3)           // xm'
{
    constexpr int KTILES = 8;
    constexpr int K = 512;
    __shared__ f16 Asm[2][4096];

    const int row0 = blockIdx.x * 64;
    const int tid = threadIdx.x;
    const int wv = tid >> 6;
    const int l = tid & 63;

    f32x4 acc[4][4] = {};

    const int sr = tid >> 2;
    const int sc0 = (tid & 3) * 16;
    const int grow = row0 + sr;
    const bool rok = grow < NNODES;
    const int lane_base0 =
        (((sc0 >> 5) * 4 + (sr >> 4)) * 64 + (sr & 15) + (((sc0 & 31) >> 3) * 16)) * 8;
    const int lane_base1 = lane_base0 + 128;

    const f16* bp[4];
    #pragma unroll
    for (int cf = 0; cf < 4; ++cf)
        bp[cf] = Wt + (size_t)(wv * 64 + cf * 16 + (l & 15)) * K + ((l >> 4) * 8);

    struct SReg { f16x8 h0, h1; };
    SReg RA, RB;

    auto LOAD = [&](SReg& r, int kt) {
        if (!rok) return;
        const int k0 = kt * 64 + sc0;
        const f16* p = (k0 < HDIM) ? (A3 + (size_t)grow * HDIM + k0)
                                   : (A4 + (size_t)grow * HDIM + (k0 - HDIM));
        r.h0 = *(const f16x8*)p;  r.h1 = *(const f16x8*)(p + 8);
    };

    auto COMMIT = [&](const SReg& r, int b) {
        f16x8 av0, av1;
        #pragma unroll
        for (int i = 0; i < 8; ++i) { av0[i] = (f16)0.f; av1[i] = (f16)0.f; }
        if (rok) { av0 = r.h0; av1 = r.h1; }
        *(f16x8*)(&Asm[b][lane_base0]) = av0;
        *(f16x8*)(&Asm[b][lane_base1]) = av1;
    };

    auto TILE = [&](int b, int kt) {
        f16x8 af[4][2];
        #pragma unroll
        for (int rf = 0; rf < 4; ++rf)
            #pragma unroll
            for (int kb = 0; kb < 2; ++kb)
                af[rf][kb] = *(const f16x8*)(&Asm[b][((kb * 4 + rf) * 64 + l) * 8]);
        f16x8 bfr[4][2];
        #pragma unroll
        for (int cf = 0; cf < 4; ++cf) {
            bfr[cf][0] = *(const f16x8*)(bp[cf] + kt * 64);
            bfr[cf][1] = *(const f16x8*)(bp[cf] + kt * 64 + 32);
        }
        #pragma unroll
        for (int cf = 0; cf < 4; ++cf)
            #pragma unroll
            for (int rf = 0; rf < 4; ++rf)
                #pragma unroll
                for (int kb = 0; kb < 2; ++kb)
                    acc[rf][cf] = __builtin_amdgcn_mfma_f32_16x16x32_f16(
                        af[rf][kb], bfr[cf][kb], acc[rf][cf], 0, 0, 0);
    };

    LOAD(RA, 0);
    COMMIT(RA, 0);
    LOAD(RB, 1);
    #pragma unroll
    for (int kt2 = 0; kt2 < KTILES; kt2 += 2) {
        __syncthreads();
        TILE(0, kt2);
        COMMIT(RB, 1);
        if (kt2 + 2 < KTILES) LOAD(RA, kt2 + 2);
        __syncthreads();
        TILE(1, kt2 + 1);
        if (kt2 + 2 < KTILES) COMMIT(RA, 0);
        if (kt2 + 3 < KTILES) LOAD(RB, kt2 + 3);
    }

    #pragma unroll
    for (int rf = 0; rf < 4; ++rf) {
        #pragma unroll
        for (int j = 0; j < 4; ++j) {
            const int row = row0 + rf * 16 + ((l >> 4) * 4) + j;
            if (row >= NNODES) continue;
            #pragma unroll
            for (int cf = 0; cf < 4; ++cf) {
                const int col = wv * 64 + cf * 16 + (l & 15);
                const float r = fmaxf(acc[rf][cf][j] + bias[col], 0.f);
                Cf[(size_t)row * ldc + col] = r;
                Ch[(size_t)row * HDIM + col] = (f16)r;
                Ch3[(size_t)row * HDIM + col] =
                    (f16)(r * (float)Mh[(size_t)row * HDIM + col]);
            }
        }
    }
}

// ---------------------------------------------------------------------------
// lin0 GEMM (R12): K-split x4, f16 partials.
// ---------------------------------------------------------------------------
template<int KTILES>
__global__ __launch_bounds__(256) void lin0_k(
    const float* __restrict__ A1, int lda1,
    const f16*  __restrict__ WtBase,
    f16* __restrict__ parts)
{
    constexpr int K = KTILES * 64;     // 320
    __shared__ f16 Asm[2][4096];

    const int row0 = blockIdx.x * 64;
    const int by = blockIdx.y;
    const int tid = threadIdx.x;
    const int wv = tid >> 6;
    const int l = tid & 63;

    f32x4 acc[4][4] = {};

    const int sr = tid >> 2;
    const int sc0 = (tid & 3) * 16;
    const int grow = row0 + sr;
    const bool rok = grow < NNODES;
    const int kg = by * K;
    const int lane_base0 =
        (((sc0 >> 5) * 4 + (sr >> 4)) * 64 + (sr & 15) + (((sc0 & 31) >> 3) * 16)) * 8;
    const int lane_base1 = lane_base0 + 128;

    const f16* Wsel = WtBase + (size_t)by * 256 * K;
    const f16* bp[4];
    #pragma unroll
    for (int cf = 0; cf < 4; ++cf)
        bp[cf] = Wsel + (size_t)(wv * 64 + cf * 16 + (l & 15)) * K + ((l >> 4) * 8);

    struct SReg { float4 f0, f1, f2, f3; };
    SReg RA, RB;

    auto LOAD = [&](SReg& r, int kt) {
        if (!rok) return;
        const float* p = A1 + (size_t)grow * lda1 + kg + kt * 64 + sc0;
        r.f0 = *(const float4*)(p + 0);  r.f1 = *(const float4*)(p + 4);
        r.f2 = *(const float4*)(p + 8);  r.f3 = *(const float4*)(p + 12);
    };

    auto COMMIT = [&](const SReg& r, int b) {
        f16x8 av0, av1;
        #pragma unroll
        for (int i = 0; i < 8; ++i) { av0[i] = (f16)0.f; av1[i] = (f16)0.f; }
        if (rok) {
            av0[0]=(f16)r.f0.x; av0[1]=(f16)r.f0.y; av0[2]=(f16)r.f0.z; av0[3]=(f16)r.f0.w;
            av0[4]=(f16)r.f1.x; av0[5]=(f16)r.f1.y; av0[6]=(f16)r.f1.z; av0[7]=(f16)r.f1.w;
            av1[0]=(f16)r.f2.x; av1[1]=(f16)r.f2.y; av1[2]=(f16)r.f2.z; av1[3]=(f16)r.f2.w;
            av1[4]=(f16)r.f3.x; av1[5]=(f16)r.f3.y; av1[6]=(f16)r.f3.z; av1[7]=(f16)r.f3.w;
        }
        *(f16x8*)(&Asm[b][lane_base0]) = av0;
        *(f16x8*)(&Asm[b][lane_base1]) = av1;
    };

    auto TILE = [&](int b, int kt) {
        f16x8 af[4][2];
        #pragma unroll
        for (int rf = 0; rf < 4; ++rf)
            #pragma unroll
            for (int kb = 0; kb < 2; ++kb)
                af[rf][kb] = *(const f16x8*)(&Asm[b][((kb * 4 + rf) * 64 + l) * 8]);
        f16x8 bfr[4][2];
        #pragma unroll
        for (int cf = 0; cf < 4; ++cf) {
            bfr[cf][0] = *(const f16x8*)(bp[cf] + kt * 64);
            bfr[cf][1] = *(const f16x8*)(bp[cf] + kt * 64 + 32);
        }
        #pragma unroll
        for (int cf = 0; cf < 4; ++cf)
            #pragma unroll
            for (int rf = 0; rf < 4; ++rf)
                #pragma unroll
                for (int kb = 0; kb < 2; ++kb)
                    acc[rf][cf] = __builtin_amdgcn_mfma_f32_16x16x32_f16(
                        af[rf][kb], bfr[cf][kb], acc[rf][cf], 0, 0, 0);
    };

    LOAD(RA, 0);
    COMMIT(RA, 0);
    if (KTILES > 1) LOAD(RB, 1);
    #pragma unroll
    for (int kt2 = 0; kt2 < KTILES; kt2 += 2) {
        __syncthreads();
        TILE(0, kt2);
        if (kt2 + 1 < KTILES) COMMIT(RB, 1);
        if (kt2 + 2 < KTILES) LOAD(RA, kt2 + 2);
        if (kt2 + 1 < KTILES) {
            __syncthreads();
            TILE(1, kt2 + 1);
            if (kt2 + 2 < KTILES) COMMIT(RA, 0);
            if (kt2 + 3 < KTILES) LOAD(RB, kt2 + 3);
        }
    }

    f16* Ph = parts + (size_t)by * NNODES * HDIM;
    #pragma unroll
    for (int rf = 0; rf < 4; ++rf) {
        #pragma unroll
        for (int j = 0; j < 4; ++j) {
            const int row = row0 + rf * 16 + ((l >> 4) * 4) + j;
            if (row >= NNODES) continue;
            #pragma unroll
            for (int cf = 0; cf < 4; ++cf) {
                const int col = wv * 64 + cf * 16 + (l & 15);
                Ph[(size_t)row * HDIM + col] = (f16)acc[rf][cf][j];
            }
        }
    }
}

__global__ __launch_bounds__(256) void combine4_k(
    const f16* __restrict__ parts, const float* __restrict__ b,
    f16* __restrict__ xh)
{
    const int t = blockIdx.x * 256 + threadIdx.x;
    const int row = t >> 6;
    const int c = (t & 63) * 4;
    if (row >= NNODES) return;
    const size_t NH = (size_t)NNODES * HDIM;
    const size_t off = (size_t)row * HDIM + c;
    f16x4 p0 = *(const f16x4*)(parts + off);
    f16x4 p1 = *(const f16x4*)(parts + NH + off);
    f16x4 p2 = *(const f16x4*)(parts + 2 * NH + off);
    f16x4 p3 = *(const f16x4*)(parts + 3 * NH + off);
    const float4 bb = *(const float4*)(b + c);
    f16x4 r;
    r[0] = (f16)((float)p0[0] + (float)p1[0] + (float)p2[0] + (float)p3[0] + bb.x);
    r[1] = (f16)((float)p0[1] + (float)p1[1] + (float)p2[1] + (float)p3[1] + bb.y);
    r[2] = (f16)((float)p0[2] + (float)p1[2] + (float)p2[2] + (float)p3[2] + bb.z);
    r[3] = (f16)((float)p0[3] + (float)p1[3] + (float)p2[3] + (float)p3[3] + bb.w);
    *(f16x4*)(xh + off) = r;
}

// ---------------------------------------------------------------------------
// ONE fused weight-pack kernel (R12 layout, verified).
// ---------------------------------------------------------------------------
__global__ __launch_bounds__(256) void pack_all_k(
    const float* __restrict__ lin0_W,
    const float* __restrict__ W2, const float* __restrict__ W1,
    const float* __restrict__ W3,
    const float* __restrict__ Wn, const float* __restrict__ Wr,
    f16* __restrict__ dst)
{
    int idx = blockIdx.x * 256 + threadIdx.x;
    const int total = 327680 + 524288 + 262144 + 524288;
    if (idx >= total) return;
    f16* d = dst + idx;
    if (idx < 327680) {                       // lin0 K-quarter slices
        const int q = idx / 81920;
        int r = idx % 81920;
        const int col = r / 320, k = r % 320;
        *d = (f16)lin0_W[(size_t)(k + q * 320) * 256 + col];
        return;
    }
    idx -= 327680;
    if (idx < 524288) {                       // WH = [W2;W1]
        const int i = idx / 131072;
        int r = idx % 131072;
        const int col = r / 512, k = r % 512;
        *d = (f16)(k < 256 ? W2[(size_t)i * 65536 + k * 256 + col]
                           : W1[(size_t)i * 65536 + (k - 256) * 256 + col]);
        return;
    }
    idx -= 524288;
    if (idx < 262144) {                       // W3t
        const int i = idx / 65536;
        int r = idx % 65536;
        const int col = r / 256, k = r % 256;
        *d = (f16)W3[(size_t)i * 65536 + k * 256 + col];
        return;
    }
    idx -= 262144;                            // WtC = [Wn;Wr]
    const int i = idx / 131072; int r = idx % 131072;
    const int col = r / 512, k = r % 512;
    *d = (f16)(k < 256 ? Wn[(size_t)i * 65536 + k * 256 + col]
                       : Wr[(size_t)i * 65536 + (k - 256) * 256 + col]);
}

// ---------------------------------------------------------------------------
// CSR build (counts doubles as degree table)
// ---------------------------------------------------------------------------
__global__ __launch_bounds__(256) void count_k(
    const int* __restrict__ dstIdx, int* __restrict__ counts)
{
    const int e = blockIdx.x * 256 + threadIdx.x;
    if (e < NEDGES) atomicAdd(&counts[dstIdx[e]], 1);
}

__global__ __launch_bounds__(1024) void scan_k(
    const int* __restrict__ counts, int* __restrict__ starts)
{
    __shared__ int sm[1024];
    __shared__ int s_off;
    if (threadIdx.x == 0) s_off = 0;
    __syncthreads();
    for (int base = 0; base < NNODES; base += 1024) {
        const int i = base + threadIdx.x;
        const int v = (i < NNODES) ? counts[i] : 0;
        sm[threadIdx.x] = v;
        __syncthreads();
        for (int ofs = 1; ofs < 1024; ofs <<= 1) {
            const int t = (threadIdx.x >= ofs) ? sm[threadIdx.x - ofs] : 0;
            __syncthreads();
            sm[threadIdx.x] += t;
            __syncthreads();
        }
        const int incl = sm[threadIdx.x];
        const int off = s_off;
        if (i < NNODES) starts[i] = off + incl - v;
        __syncthreads();
        if (threadIdx.x == 1023) s_off = off + incl;
        __syncthreads();
    }
    if (threadIdx.x == 0) starts[NNODES] = s_off;
}

__global__ __launch_bounds__(256) void fillcsr_k(
    const int* __restrict__ srcIdx, const int* __restrict__ dstIdx,
    int* __restrict__ cursor, int* __restrict__ csr)
{
    const int e = blockIdx.x * 256 + threadIdx.x;
    if (e >= NEDGES) return;
    const int d = dstIdx[e];
    const int p = atomicAdd(&cursor[d], 1);
    csr[p] = srcIdx[e];
}

// ---------------------------------------------------------------------------
// gather-sum (R10-verified): one wave per node, f16 rows, f32 accum, unroll-4
// ---------------------------------------------------------------------------
__global__ __launch_bounds__(256) void gather_g_k(
    const f16* __restrict__ rows, const int* __restrict__ csr,
    const int* __restrict__ starts, f16* __restrict__ outp)
{
    const int node = (blockIdx.x * 256 + threadIdx.x) >> 6;
    const int lane = threadIdx.x & 63;
    if (node >= NNODES) return;
    const int e0 = starts[node], e1 = starts[node + 1];
    float a0=0,a1=0,a2=0,a3=0, b0=0,b1=0,b2=0,b3=0;
    int e = e0;
    for (; e + 3 < e1; e += 4) {
        const int s0=csr[e], s1=csr[e+1], s2=csr[e+2], s3=csr[e+3];
        f16x4 v0 = *(const f16x4*)(rows + (size_t)s0 * HDIM + lane * 4);
        f16x4 v1 = *(const f16x4*)(rows + (size_t)s1 * HDIM + lane * 4);
        f16x4 v2 = *(const f16x4*)(rows + (size_t)s2 * HDIM + lane * 4);
        f16x4 v3 = *(const f16x4*)(rows + (size_t)s3 * HDIM + lane * 4);
        a0 += (float)v0[0] + (float)v2[0]; a1 += (float)v0[1] + (float)v2[1];
        a2 += (float)v0[2] + (float)v2[2]; a3 += (float)v0[3] + (float)v2[3];
        b0 += (float)v1[0] + (float)v3[0]; b1 += (float)v1[1] + (float)v3[1];
        b2 += (float)v1[2] + (float)v3[2]; b3 += (float)v1[3] + (float)v3[3];
    }
    for (; e < e1; ++e) {
        const int s0 = csr[e];
        f16x4 v0 = *(const f16x4*)(rows + (size_t)s0 * HDIM + lane * 4);
        a0 += (float)v0[0]; a1 += (float)v0[1]; a2 += (float)v0[2]; a3 += (float)v0[3];
    }
    f16x4 r;
    r[0] = (f16)(a0 + b0); r[1] = (f16)(a1 + b1);
    r[2] = (f16)(a2 + b2); r[3] = (f16)(a3 + b3);
    *(f16x4*)(outp + (size_t)node * HDIM + lane * 4) = r;
}

__global__ __launch_bounds__(256) void fill1_k(float* __restrict__ p, int n)
{
    const int t = blockIdx.x * 256 + threadIdx.x;
    if (t < n) p[t] = 1.0f;
}

// ---------------------------------------------------------------------------
extern "C" void kernel_launch(void* const* d_in, const int* in_sizes, int n_in,
                              void* d_out, int out_size, void* d_ws, size_t ws_size,
                              hipStream_t stream)
{
    const int*   edge   = (const int*)d_in[1];
    const int*   src    = edge;
    const int*   dst    = edge + NEDGES;
    const float* esm    = (const float*)d_in[2];
    const float* lin0_W = (const float*)d_in[4];
    const float* lin0_b = (const float*)d_in[5];
    const float* wc_W1  = (const float*)d_in[6];
    const float* wc_b1  = (const float*)d_in[7];
    const float* wc_W2  = (const float*)d_in[8];
    const float* wc_b2  = (const float*)d_in[9];
    const float* wc_W3  = (const float*)d_in[10];
    const float* wc_b3  = (const float*)d_in[11];
    const float* sc_Wn  = (const float*)d_in[12];
    const float* sc_bn  = (const float*)d_in[13];
    const float* sc_Wr  = (const float*)d_in[14];
    float* out = (float*)d_out;

    const size_t NH = (size_t)NNODES * HDIM;
    f16* parts = (f16*)d_ws;              // 4 x NH lin0 partials; reused:
    f16* aggx  = parts;                   //   p0 -> aggx
    f16* xg    = parts + NH;              //   p1 -> xg
    f16* agg2  = parts + 2 * NH;          //   p2 -> agg2
    f16* xh    = parts + 4 * NH;          // persistent x
    f16* xm    = xh + NH;                 // persistent x*mask
    f16* maskh = xm + NH;                 // persistent mask
    f16* wpack = maskh + NH;
    f16* lin0t = wpack;                   // 327680
    f16* WH    = lin0t + 327680;          // 524288
    f16* W3t   = WH + 524288;             // 262144
    f16* WtC   = W3t + 262144;            // 524288
    int* iws    = (int*)(WtC + 524288);
    int* counts = iws;                    // degree table
    int* starts = iws + NNODES;
    int* cursor = iws + 2 * NNODES + 1;
    int* csr    = iws + 3 * NNODES + 2;

    const dim3 blk(256);
    const int gemmGrid = (NNODES + 63) / 64;           // 782
    const int edgeGrid = (NEDGES + 255) / 256;
    const int waveGrid = (NNODES * 64) / 256;          // 12500

    // ---- CSR build
    hipMemsetAsync(counts, 0, NNODES * sizeof(int), stream);
    count_k<<<edgeGrid, blk, 0, stream>>>(dst, counts);
    scan_k<<<1, 1024, 0, stream>>>(counts, starts);
    hipMemcpyAsync(cursor, starts, NNODES * sizeof(int),
                   hipMemcpyDeviceToDevice, stream);
    fillcsr_k<<<edgeGrid, blk, 0, stream>>>(src, dst, cursor, csr);

    // ---- all weight packs in ONE dispatch
    pack_all_k<<<(1638400 + 255) / 256, blk, 0, stream>>>(
        lin0_W, wc_W2, wc_W1, wc_W3, sc_Wn, sc_Wr, wpack);

    // ---- lin0 K-split x4 -> f16 partials -> combine into xh
    lin0_k<5><<<dim3(gemmGrid, 4), blk, 0, stream>>>(esm, FIN, lin0t, parts);
    combine4_k<<<waveGrid, blk, 0, stream>>>(parts, lin0_b, xh);

    for (int i = 0; i < NLAYERS; ++i) {
        const size_t bo = (size_t)i * HDIM;
        const f16* wh = WH + (size_t)i * 131072;
        const f16* w3 = W3t + (size_t)i * 65536;
        const f16* wc = WtC + (size_t)i * 131072;
        const f16* xmtab = (i == 0) ? xh : xm;   // layer 0: mask is None

        // aggx = segment_sum(xm[src], dst)
        gather_g_k<<<waveGrid, blk, 0, stream>>>(xmtab, csr, starts, aggx);
        // fused: h = relu([aggx|xm]@[W2;W1]+deg*b2+b1) in LDS;
        //        mask = sigmoid(h@W3+b3); xg = xh*mask
        hm_k<<<gemmGrid, blk, 0, stream>>>(
            aggx, xmtab, xh, counts, wh, w3,
            wc_b2 + bo, wc_b1 + bo, wc_b3 + bo, maskh, xg);
        // agg2 = segment_sum(xg[src], dst)
        gather_g_k<<<waveGrid, blk, 0, stream>>>(xg, csr, starts, agg2);
        // x' = relu([agg2|xh]@[Wn;Wr]+bn) -> out slice, xh (in-place), xm'
        cath2_k<<<gemmGrid, blk, 0, stream>>>(
            agg2, xh, maskh, wc, sc_bn + bo,
            out + (size_t)i * HDIM, LDOUT, xh, xm);
    }

    // node_mask: all true
    const size_t maskOff = (size_t)NNODES * LDOUT;
    fill1_k<<<(NNODES + 255) / 256, blk, 0, stream>>>(out + maskOff, NNODES);
}